// Round 8
// baseline (344.658 us; speedup 1.0000x reference)
//
#include <hip/hip_runtime.h>
#include <stdint.h>

#define BATCH 2000000
#define NHID  14
#define NT    4                         // 16-row n-tiles per wave -> 64 rows/wave
#define NWAVE 12                        // 768-thread block: 3 waves/SIMD (reg cap 170)
#define ROWS_PER_BLOCK (NWAVE * 16 * NT)                         // 768
#define NTILES ((BATCH + ROWS_PER_BLOCK - 1) / ROWS_PER_BLOCK)   // 2605
#define NSLOT 118                       // 4 (L0) + 14*8 (hidden) + 2 (out) A-fragments
#define BIAS_OFF (NSLOT * 64 * 16)      // bias array after frags
#define LDS_BYTES (BIAS_OFF + 16 * 64 * 4)   // 120832 + 4096 = 124928 B

typedef float    v4f  __attribute__((ext_vector_type(4)));
typedef _Float16 v8h  __attribute__((ext_vector_type(8)));
typedef __fp16   v2p  __attribute__((ext_vector_type(2)));
typedef uint32_t v4u  __attribute__((ext_vector_type(4)));

// x32 MFMA layouts: A[m=lane&15][k=quad*8+j], B[k=quad*8+j][n=lane&15],
// C/D[row=quad*4+reg][col=lane&15].
// k-permutation: A's k-columns stored permuted so the next-layer B fragment is
// exactly the concatenation of two packed C tiles (no cross-lane ops).
// Slot kappa = 32*t' + 8*q + j holds actual feature kown(kappa):
//   s = 8*t' + j ; kown = 16*(s>>2) + 4*q + (s&3)
// Bias now enters as the MFMA C operand (per-layer, fp32) -> no zero-C
// materialization per n-tile and no bias column in the weights.
__device__ __forceinline__ int kown(int kappa) {
    int s = ((kappa >> 5) << 3) | (kappa & 7);
    int q = (kappa >> 3) & 3;
    return ((s >> 2) << 4) | (q * 4 + (s & 3));
}

__device__ __forceinline__ uint32_t pk(float a, float b) {      // v_cvt_pkrtz_f16_f32
    union { v2p v; uint32_t u; } c;
    c.v = __builtin_amdgcn_cvt_pkrtz(a, b);
    return c.u;
}
__device__ __forceinline__ uint32_t relu_pk(float a, float b) { // pkrtz + v_pk_max_f16
    v2p z = { (__fp16)0.0f, (__fp16)0.0f };
    union { v2p v; uint32_t u; } c;
    c.v = __builtin_amdgcn_cvt_pkrtz(a, b);
    c.v = __builtin_elementwise_max(c.v, z);
    return c.u;
}

// C tiles (4 x v4f) -> two x32 B fragments (relu + f16 pack). 16 VALU ops.
__device__ __forceinline__ void pack2(const v4f* acc, v8h* Bv) {
    union { v4u u; v8h h; } c0, c1;
    c0.u.x = relu_pk(acc[0][0], acc[0][1]);
    c0.u.y = relu_pk(acc[0][2], acc[0][3]);
    c0.u.z = relu_pk(acc[1][0], acc[1][1]);
    c0.u.w = relu_pk(acc[1][2], acc[1][3]);
    c1.u.x = relu_pk(acc[2][0], acc[2][1]);
    c1.u.y = relu_pk(acc[2][2], acc[2][3]);
    c1.u.z = relu_pk(acc[3][0], acc[3][1]);
    c1.u.w = relu_pk(acc[3][2], acc[3][3]);
    Bv[0] = c0.h;
    Bv[1] = c1.h;
}

extern "C" __global__ __launch_bounds__(768, 3)
void mlp16(const float* __restrict__ x,
           const float* __restrict__ W0, const float* __restrict__ b0,
           const float* __restrict__ Wh, const float* __restrict__ bh,
           const float* __restrict__ Wo, const float* __restrict__ bo,
           float* __restrict__ out)
{
    extern __shared__ char smem_raw[];
    v8h*   frag = (v8h*)smem_raw;               // [slot][lane], 16 B per lane
    float* bias = (float*)(smem_raw + BIAS_OFF); // [16 layers][64 rows]

    const int tid  = threadIdx.x;
    const int lane = tid & 63;
    const int wv   = tid >> 6;
    const int l15  = lane & 15;
    const int quad = lane >> 4;

    // ------------- one-time weight staging (no bias columns) -------------
    for (int s = wv; s < NSLOT; s += NWAVE) {
        float v[8];
        if (s < 4) {                    // layer 0: natural k, K=32 (k<16 real)
            int m = s * 16 + l15;
            #pragma unroll
            for (int j = 0; j < 8; ++j) {
                int kap = quad * 8 + j;
                v[j] = (m < 50 && kap < 16) ? W0[m * 16 + kap] : 0.f;
            }
        } else if (s < 116) {           // hidden: permuted k
            int h = s - 4, l = h >> 3, t = (h >> 2) & 1, mt = h & 3;
            int m = mt * 16 + l15;
            const float* W = Wh + l * 2500;
            #pragma unroll
            for (int j = 0; j < 8; ++j) {
                int ko = kown(t * 32 + quad * 8 + j);
                v[j] = (m < 50 && ko < 50) ? W[m * 50 + ko] : 0.f;
            }
        } else {                        // output: permuted k, m<4
            int t = s - 116, m = l15;
            #pragma unroll
            for (int j = 0; j < 8; ++j) {
                int ko = kown(t * 32 + quad * 8 + j);
                v[j] = (m < 4 && ko < 50) ? Wo[m * 50 + ko] : 0.f;
            }
        }
        v8h fv;
        #pragma unroll
        for (int j = 0; j < 8; ++j) fv[j] = (_Float16)v[j];   // RNE
        frag[s * 64 + lane] = fv;
    }
    // bias array: [layer 0..15][row 0..63] fp32
    for (int i = tid; i < 16 * 64; i += NWAVE * 64) {
        int l = i >> 6, r = i & 63;
        float bv = 0.f;
        if (l == 0)       { if (r < 50) bv = b0[r]; }
        else if (l <= 14) { if (r < 50) bv = bh[(l - 1) * 50 + r]; }
        else              { if (r < 4)  bv = bo[r]; }
        bias[i] = bv;
    }
    __syncthreads();                    // only barrier in the kernel

    for (int tile = blockIdx.x; tile < NTILES; tile += gridDim.x) {
        const int rowbase = tile * ROWS_PER_BLOCK + wv * (16 * NT);
        v8h Bv[NT][2];                  // activations, registers only
        v4f acc[2][4];                  // ping-pong accumulators (software pipeline)

        // ---- layer 0: K=32 frag (k<16 real), bias as C, 4 MFMA/n-tile ----
        {
            v8h A0[4];
            v4f bc[4];
            #pragma unroll
            for (int mt = 0; mt < 4; ++mt) {
                A0[mt] = frag[mt * 64 + lane];
                bc[mt] = *(const v4f*)(bias + 0 * 64 + mt * 16 + quad * 4);
            }
            union { v4u u; v8h h; } bx[NT];
            #pragma unroll
            for (int nt = 0; nt < NT; ++nt) {       // issue all loads first
                int r  = rowbase + nt * 16 + l15;
                int rc = r < BATCH ? r : BATCH - 1;
                bx[nt].u = (v4u){0u, 0u, 0u, 0u};
                if (quad < 2) {
                    const float* xp = x + (size_t)rc * 16 + quad * 8;
                    v4f xa = *(const v4f*)xp;
                    v4f xb = *(const v4f*)(xp + 4);
                    bx[nt].u.x = pk(xa[0], xa[1]);
                    bx[nt].u.y = pk(xa[2], xa[3]);
                    bx[nt].u.z = pk(xb[0], xb[1]);
                    bx[nt].u.w = pk(xb[2], xb[3]);
                }
            }
            #pragma unroll
            for (int mt = 0; mt < 4; ++mt)
                acc[0][mt] = __builtin_amdgcn_mfma_f32_16x16x32_f16(A0[mt], bx[0].h, bc[mt], 0, 0, 0);
            #pragma unroll
            for (int nt = 1; nt < NT; ++nt) {
                #pragma unroll
                for (int mt = 0; mt < 4; ++mt)
                    acc[nt & 1][mt] = __builtin_amdgcn_mfma_f32_16x16x32_f16(A0[mt], bx[nt].h, bc[mt], 0, 0, 0);
                pack2(acc[(nt - 1) & 1], Bv[nt - 1]);
            }
            pack2(acc[(NT - 1) & 1], Bv[NT - 1]);
        }

        // ---- 14 hidden layers: pipelined — MFMAs of nt issue before pack of nt-1 ----
        for (int l = 0; l < NHID; ++l) {
            v8h A[2][4];
            v4f bc[4];
            const v8h* ab = frag + (4 + l * 8) * 64 + lane;
            #pragma unroll
            for (int t = 0; t < 2; ++t)
                #pragma unroll
                for (int mt = 0; mt < 4; ++mt) A[t][mt] = ab[(t * 4 + mt) * 64]; // ds_read_b128
            #pragma unroll
            for (int mt = 0; mt < 4; ++mt)
                bc[mt] = *(const v4f*)(bias + (1 + l) * 64 + mt * 16 + quad * 4);

            #pragma unroll
            for (int mt = 0; mt < 4; ++mt)
                acc[0][mt] = __builtin_amdgcn_mfma_f32_16x16x32_f16(A[0][mt], Bv[0][0], bc[mt], 0, 0, 0);
            #pragma unroll
            for (int mt = 0; mt < 4; ++mt)
                acc[0][mt] = __builtin_amdgcn_mfma_f32_16x16x32_f16(A[1][mt], Bv[0][1], acc[0][mt], 0, 0, 0);
            #pragma unroll
            for (int nt = 1; nt < NT; ++nt) {
                #pragma unroll
                for (int mt = 0; mt < 4; ++mt)
                    acc[nt & 1][mt] = __builtin_amdgcn_mfma_f32_16x16x32_f16(A[0][mt], Bv[nt][0], bc[mt], 0, 0, 0);
                #pragma unroll
                for (int mt = 0; mt < 4; ++mt)
                    acc[nt & 1][mt] = __builtin_amdgcn_mfma_f32_16x16x32_f16(A[1][mt], Bv[nt][1], acc[nt & 1][mt], 0, 0, 0);
                pack2(acc[(nt - 1) & 1], Bv[nt - 1]);   // Bv[nt-1] already consumed
            }
            pack2(acc[(NT - 1) & 1], Bv[NT - 1]);
        }

        // ---- output layer: 2 MFMA/n-tile, bias as C; rows 0-3 = quad-0 regs ----
        {
            v8h Ao[2];
            #pragma unroll
            for (int t = 0; t < 2; ++t) Ao[t] = frag[(116 + t) * 64 + lane];
            v4f bco = *(const v4f*)(bias + 15 * 64 + quad * 4);
            #pragma unroll
            for (int nt = 0; nt < NT; ++nt) {
                v4f a = __builtin_amdgcn_mfma_f32_16x16x32_f16(Ao[0], Bv[nt][0], bco, 0, 0, 0);
                a     = __builtin_amdgcn_mfma_f32_16x16x32_f16(Ao[1], Bv[nt][1], a, 0, 0, 0);
                int r = rowbase + nt * 16 + l15;
                if (quad == 0 && r < BATCH)
                    *(v4f*)(out + (size_t)r * 4) = a;   // 16B store per row
            }
        }
    }
}

extern "C" void kernel_launch(void* const* d_in, const int* in_sizes, int n_in,
                              void* d_out, int out_size, void* d_ws, size_t ws_size,
                              hipStream_t stream)
{
    (void)in_sizes; (void)n_in; (void)d_ws; (void)ws_size; (void)out_size;
    (void)hipFuncSetAttribute(reinterpret_cast<const void*>(mlp16),
                              hipFuncAttributeMaxDynamicSharedMemorySize, LDS_BYTES);
    mlp16<<<256, 768, LDS_BYTES, stream>>>(
        (const float*)d_in[0], (const float*)d_in[1], (const float*)d_in[2],
        (const float*)d_in[3], (const float*)d_in[4], (const float*)d_in[5],
        (const float*)d_in[6], (float*)d_out);
}